// Round 1
// baseline (2202.908 us; speedup 1.0000x reference)
//
#include <hip/hip_runtime.h>
#include <stdint.h>

#define NTRAIN 100000
#define BATCH  2048
#define DIM    64
#define KNN    128
#define CAP    3072      // candidate capacity per row
#define NSAMP  2048      // sampled points for threshold estimate
#define KSAMP  24        // take 24th smallest of sample as threshold
#define BM     32        // rows per distance block
#define TNS    256       // training points per tile
#define NCHUNK 8
#define CHUNK  12500

// workspace layout (bytes); total ~52.4 MB
#define OFF_THR   (0)
#define OFF_CNT   (64*1024)
#define OFF_SEL   (128*1024)
#define OFF_CAND  (2*1024*1024)   // 2048*3072*8 ; front 16.8MB doubles as sampleV (used before cand)

// ---------------- sample-distance kernel: v = |t|^2 - 2 x.t for 2048 strided samples ----------------
__global__ __launch_bounds__(256) void ksample(const float* __restrict__ x,
                                               const float* __restrict__ tX,
                                               float* __restrict__ sampleV)
{
    __shared__ float xsT[DIM][36];
    __shared__ float tT[DIM][TNS + 4];
    __shared__ float tns[TNS];
    const int tid = threadIdx.x;
    const int rb  = blockIdx.x * BM;

    { // stage x rows transposed: thread -> (row = tid&31, 8 dims)
        int r = tid & 31, d0 = (tid >> 5) * 8;
        const float4* xp = (const float4*)(x + (size_t)(rb + r) * DIM + d0);
        float4 v0 = xp[0], v1 = xp[1];
        xsT[d0+0][r]=v0.x; xsT[d0+1][r]=v0.y; xsT[d0+2][r]=v0.z; xsT[d0+3][r]=v0.w;
        xsT[d0+4][r]=v1.x; xsT[d0+5][r]=v1.y; xsT[d0+6][r]=v1.z; xsT[d0+7][r]=v1.w;
    }
    const int a = tid >> 5;   // row group (4 rows)
    const int b = tid & 31;   // col group (8 pts)

    for (int t0 = 0; t0 < NSAMP; t0 += TNS) {
        __syncthreads();
        { // stage one sampled point per thread (transposed) + its norm
            int s = t0 + tid;
            int p = (int)(((long long)s * NTRAIN) >> 11);
            const float4* tp = (const float4*)(tX + (size_t)p * DIM);
            float nrm = 0.f;
            #pragma unroll
            for (int q = 0; q < 16; ++q) {
                float4 v = tp[q];
                int d = q * 4;
                tT[d+0][tid]=v.x; tT[d+1][tid]=v.y; tT[d+2][tid]=v.z; tT[d+3][tid]=v.w;
                nrm = fmaf(v.x,v.x,nrm); nrm = fmaf(v.y,v.y,nrm);
                nrm = fmaf(v.z,v.z,nrm); nrm = fmaf(v.w,v.w,nrm);
            }
            tns[tid] = nrm;
        }
        __syncthreads();

        float acc[4][8];
        #pragma unroll
        for (int r=0;r<4;++r)
            #pragma unroll
            for (int c=0;c<8;++c) acc[r][c]=0.f;

        #pragma unroll 4
        for (int d = 0; d < DIM; ++d) {
            float4 xv  = *(const float4*)&xsT[d][a*4];
            float4 t0v = *(const float4*)&tT[d][b*8];
            float4 t1v = *(const float4*)&tT[d][b*8+4];
            float xr[4] = {xv.x,xv.y,xv.z,xv.w};
            float tv[8] = {t0v.x,t0v.y,t0v.z,t0v.w,t1v.x,t1v.y,t1v.z,t1v.w};
            #pragma unroll
            for (int r=0;r<4;++r)
                #pragma unroll
                for (int c=0;c<8;++c) acc[r][c] = fmaf(xr[r], tv[c], acc[r][c]);
        }
        #pragma unroll
        for (int r=0;r<4;++r) {
            int row = rb + a*4 + r;
            float4 o0, o1;
            o0.x = tns[b*8+0] - 2.f*acc[r][0]; o0.y = tns[b*8+1] - 2.f*acc[r][1];
            o0.z = tns[b*8+2] - 2.f*acc[r][2]; o0.w = tns[b*8+3] - 2.f*acc[r][3];
            o1.x = tns[b*8+4] - 2.f*acc[r][4]; o1.y = tns[b*8+5] - 2.f*acc[r][5];
            o1.z = tns[b*8+6] - 2.f*acc[r][6]; o1.w = tns[b*8+7] - 2.f*acc[r][7];
            *(float4*)&sampleV[(size_t)row * NSAMP + t0 + b*8]     = o0;
            *(float4*)&sampleV[(size_t)row * NSAMP + t0 + b*8 + 4] = o1;
        }
    }
}

// ---------------- per-row threshold: 24th smallest sample value ----------------
__global__ __launch_bounds__(256) void kthresh(const float* __restrict__ sampleV,
                                               float* __restrict__ thrv)
{
    __shared__ float sv[NSAMP];
    __shared__ float red[8];
    const int row = blockIdx.x, tid = threadIdx.x;
    for (int s = tid; s < NSAMP; s += 256) sv[s] = sampleV[(size_t)row * NSAMP + s];
    __syncthreads();
    float lb = -1e30f;
    for (int it = 0; it < KSAMP; ++it) {
        float m = 1e30f;
        for (int s = tid; s < NSAMP; s += 256) {
            float v = sv[s];
            m = (v > lb && v < m) ? v : m;
        }
        #pragma unroll
        for (int o = 1; o < 64; o <<= 1) m = fminf(m, __shfl_xor(m, o));
        if ((tid & 63) == 0) red[tid >> 6] = m;
        __syncthreads();
        lb = fminf(fminf(red[0], red[1]), fminf(red[2], red[3]));
        __syncthreads();
    }
    if (tid == 0) thrv[row] = lb;
}

// ---------------- main distance pass: append candidates v <= thr ----------------
__global__ __launch_bounds__(256) void kdist(const float* __restrict__ x,
                                             const float* __restrict__ tX,
                                             const float* __restrict__ thrv,
                                             unsigned int* __restrict__ gcnt,
                                             uint2* __restrict__ cand)
{
    __shared__ float xsT[DIM][36];
    __shared__ float tT[DIM][TNS + 4];
    __shared__ float tns[TNS];
    __shared__ float thr_s[BM];
    const int tid = threadIdx.x;
    const int rb  = (blockIdx.x & 63) * BM;
    const int ch  = blockIdx.x >> 6;
    const int p0c = ch * CHUNK;
    const int p1c = (p0c + CHUNK < NTRAIN) ? p0c + CHUNK : NTRAIN;

    {
        int r = tid & 31, d0 = (tid >> 5) * 8;
        const float4* xp = (const float4*)(x + (size_t)(rb + r) * DIM + d0);
        float4 v0 = xp[0], v1 = xp[1];
        xsT[d0+0][r]=v0.x; xsT[d0+1][r]=v0.y; xsT[d0+2][r]=v0.z; xsT[d0+3][r]=v0.w;
        xsT[d0+4][r]=v1.x; xsT[d0+5][r]=v1.y; xsT[d0+6][r]=v1.z; xsT[d0+7][r]=v1.w;
    }
    if (tid < BM) thr_s[tid] = thrv[rb + tid];

    const int a = tid >> 5, b = tid & 31;

    for (int t0 = p0c; t0 < p1c; t0 += TNS) {
        __syncthreads();
        {
            int p  = t0 + tid;
            int ok = (p < p1c);
            int pc = ok ? p : p0c;
            const float4* tp = (const float4*)(tX + (size_t)pc * DIM);
            float nrm = 0.f;
            #pragma unroll
            for (int q = 0; q < 16; ++q) {
                float4 v = tp[q];
                int d = q * 4;
                tT[d+0][tid]=v.x; tT[d+1][tid]=v.y; tT[d+2][tid]=v.z; tT[d+3][tid]=v.w;
                nrm = fmaf(v.x,v.x,nrm); nrm = fmaf(v.y,v.y,nrm);
                nrm = fmaf(v.z,v.z,nrm); nrm = fmaf(v.w,v.w,nrm);
            }
            tns[tid] = ok ? nrm : 1e30f;   // padded tail never passes threshold
        }
        __syncthreads();

        float acc[4][8];
        #pragma unroll
        for (int r=0;r<4;++r)
            #pragma unroll
            for (int c=0;c<8;++c) acc[r][c]=0.f;

        #pragma unroll 4
        for (int d = 0; d < DIM; ++d) {
            float4 xv  = *(const float4*)&xsT[d][a*4];
            float4 t0v = *(const float4*)&tT[d][b*8];
            float4 t1v = *(const float4*)&tT[d][b*8+4];
            float xr[4] = {xv.x,xv.y,xv.z,xv.w};
            float tv[8] = {t0v.x,t0v.y,t0v.z,t0v.w,t1v.x,t1v.y,t1v.z,t1v.w};
            #pragma unroll
            for (int r=0;r<4;++r)
                #pragma unroll
                for (int c=0;c<8;++c) acc[r][c] = fmaf(xr[r], tv[c], acc[r][c]);
        }
        #pragma unroll
        for (int r=0;r<4;++r) {
            const int row = rb + a*4 + r;
            const float th = thr_s[a*4 + r];
            #pragma unroll
            for (int c=0;c<8;++c) {
                float v = tns[b*8+c] - 2.f*acc[r][c];
                if (v <= th) {
                    unsigned pos = atomicAdd(&gcnt[row], 1u);
                    if (pos < CAP) {
                        unsigned bb  = __float_as_uint(v);
                        unsigned key = (bb >> 31) ? ~bb : (bb | 0x80000000u); // order-preserving map
                        cand[(size_t)row * CAP + pos] = make_uint2(key, (unsigned)(t0 + b*8 + c));
                    }
                }
            }
        }
    }
}

// ---------------- exact top-128 from candidates (binary search on key bits) ----------------
__global__ __launch_bounds__(256) void kselect(const unsigned int* __restrict__ gcnt,
                                               const uint2* __restrict__ cand,
                                               int* __restrict__ selIdx)
{
    __shared__ unsigned ku[CAP];
    __shared__ unsigned kid[CAP];
    __shared__ int redc[8];
    __shared__ int nsel;
    __shared__ int neq;
    __shared__ unsigned eqbuf[64];
    const int row = blockIdx.x, tid = threadIdx.x;
    int n = (int)gcnt[row]; if (n > CAP) n = CAP;
    for (int i = tid; i < n; i += 256) {
        uint2 e = cand[(size_t)row * CAP + i];
        ku[i] = e.x; kid[i] = e.y;
    }
    if (tid == 0) { nsel = 0; neq = 0; }
    __syncthreads();

    unsigned lo = 0u, hi = 0xFFFFFFFFu;
    for (int it = 0; it < 32; ++it) {
        unsigned mid = (unsigned)(((unsigned long long)lo + (unsigned long long)hi) >> 1);
        int c = 0;
        for (int i = tid; i < n; i += 256) c += (ku[i] <= mid) ? 1 : 0;
        #pragma unroll
        for (int o = 1; o < 64; o <<= 1) c += __shfl_xor(c, o);
        if ((tid & 63) == 0) redc[tid >> 6] = c;
        __syncthreads();
        int tot = redc[0] + redc[1] + redc[2] + redc[3];
        __syncthreads();
        if (tot >= KNN) hi = mid; else lo = mid + 1;
    }
    const unsigned ustar = hi;

    for (int i = tid; i < n; i += 256) {
        if (ku[i] < ustar) {
            int p = atomicAdd(&nsel, 1);
            if (p < KNN) selIdx[row * KNN + p] = (int)kid[i];
        } else if (ku[i] == ustar) {
            int p = atomicAdd(&neq, 1);
            if (p < 64) eqbuf[p] = kid[i];
        }
    }
    __syncthreads();
    if (tid == 0) {
        int cl = nsel; if (cl > KNN) cl = KNN;
        int need = KNN - cl;
        int ne = neq; if (ne > 64) ne = 64;
        // lowest-index tie-break to match lax.top_k stability
        for (int t = 0; t < need && t < ne; ++t) {
            int bi = t;
            for (int u = t + 1; u < ne; ++u) if (eqbuf[u] < eqbuf[bi]) bi = u;
            unsigned tmp = eqbuf[t]; eqbuf[t] = eqbuf[bi]; eqbuf[bi] = tmp;
            selIdx[row * KNN + cl + t] = (int)eqbuf[t];
        }
        int have = cl + (need < ne ? need : ne);
        for (int k2 = have; k2 < KNN; ++k2) selIdx[row * KNN + k2] = k2; // degenerate fallback
    }
}

// ---------------- per-row GP solve: build A, Gauss-Jordan, outputs ----------------
__global__ __launch_bounds__(256) void ksolve(const float* __restrict__ x,
                                              const float* __restrict__ tX,
                                              const float* __restrict__ ty,
                                              const int* __restrict__ selIdx,
                                              const float* __restrict__ pl,
                                              const float* __restrict__ pa,
                                              float* __restrict__ out)
{
    __shared__ float nXT[DIM][KNN + 4];
    __shared__ float A[KNN][132];     // cols 0..127 matrix, col 128 rhs
    __shared__ float xs[DIM];
    __shared__ float nrm[KNN];
    __shared__ float c0[KNN];
    __shared__ float nys[KNN];
    __shared__ int   sel[KNN];
    __shared__ float redf[8];
    const int row = blockIdx.x, tid = threadIdx.x;
    const float ll = pl[0], aamp = pa[0];
    const float in2 = 1.0f / (2.0f * ll * ll);

    if (tid < KNN) sel[tid] = selIdx[row * KNN + tid];
    if (tid < DIM) xs[tid]  = x[(size_t)row * DIM + tid];
    __syncthreads();
    { // gather neighbors (transposed)
        int r = tid & 127, h = tid >> 7;
        const float4* tp = (const float4*)(tX + (size_t)sel[r] * DIM + h * 32);
        #pragma unroll
        for (int q = 0; q < 8; ++q) {
            float4 v = tp[q];
            int d = h * 32 + q * 4;
            nXT[d+0][r]=v.x; nXT[d+1][r]=v.y; nXT[d+2][r]=v.z; nXT[d+3][r]=v.w;
        }
        if (h == 0) nys[r] = ty[sel[r]];
    }
    __syncthreads();
    if (tid < KNN) { // norms + crossCov (rhs)
        float s=0.f, dt=0.f, xn=0.f;
        for (int d = 0; d < DIM; ++d) {
            float t = nXT[d][tid];
            s  = fmaf(t, t, s);
            dt = fmaf(xs[d], t, dt);
            xn = fmaf(xs[d], xs[d], xn);
        }
        nrm[tid] = s;
        float d2 = fmaxf(xn + s - 2.f*dt, 0.f);
        float cv = aamp * __expf(-d2 * in2);
        c0[tid] = cv;
        A[tid][128] = cv;
    }
    __syncthreads();
    { // build A = a*exp(-(n_i+n_j-2 g_ij)/(2 l^2)) via 8x8 register tiles
        const int ta = tid >> 4, tb = tid & 15;
        const int i0 = ta * 8, j0 = tb * 8;
        float g[8][8];
        #pragma unroll
        for (int r=0;r<8;++r)
            #pragma unroll
            for (int c=0;c<8;++c) g[r][c]=0.f;
        #pragma unroll 2
        for (int d = 0; d < DIM; ++d) {
            float4 a0 = *(const float4*)&nXT[d][i0];
            float4 a1 = *(const float4*)&nXT[d][i0+4];
            float4 b0 = *(const float4*)&nXT[d][j0];
            float4 b1 = *(const float4*)&nXT[d][j0+4];
            float av[8]={a0.x,a0.y,a0.z,a0.w,a1.x,a1.y,a1.z,a1.w};
            float bv[8]={b0.x,b0.y,b0.z,b0.w,b1.x,b1.y,b1.z,b1.w};
            #pragma unroll
            for (int r=0;r<8;++r)
                #pragma unroll
                for (int c=0;c<8;++c) g[r][c] = fmaf(av[r], bv[c], g[r][c]);
        }
        #pragma unroll
        for (int r=0;r<8;++r) {
            const float ni = nrm[i0+r];
            float tmp[8];
            #pragma unroll
            for (int c=0;c<8;++c) {
                float d2 = fmaxf(ni + nrm[j0+c] - 2.f*g[r][c], 0.f);
                tmp[c] = aamp * __expf(-d2 * in2);
            }
            *(float4*)&A[i0+r][j0]   = make_float4(tmp[0],tmp[1],tmp[2],tmp[3]);
            *(float4*)&A[i0+r][j0+4] = make_float4(tmp[4],tmp[5],tmp[6],tmp[7]);
        }
    }
    __syncthreads();
    // unscaled Gauss-Jordan (SPD, no pivoting), 1 barrier/step
    const int ei = tid >> 1, eh = tid & 1;
    for (int j = 0; j < KNN; ++j) {
        if (ei != j) {
            const float f = A[ei][j] / A[j][j];
            const int cb = (j + 4) & ~3;
            if (eh == 0) {
                for (int c = j + 1; c < cb; ++c) A[ei][c] = fmaf(-f, A[j][c], A[ei][c]);
            } else {
                A[ei][128] = fmaf(-f, A[j][128], A[ei][128]);
            }
            for (int c = cb + 4*eh; c <= 124; c += 8) {
                float4 pv = *(const float4*)&A[j][c];
                float4 cv = *(const float4*)&A[ei][c];
                cv.x = fmaf(-f, pv.x, cv.x);
                cv.y = fmaf(-f, pv.y, cv.y);
                cv.z = fmaf(-f, pv.z, cv.z);
                cv.w = fmaf(-f, pv.w, cv.w);
                *(float4*)&A[ei][c] = cv;
            }
        }
        __syncthreads();
    }
    // outputs: w[i] = rhs[i]/A[i][i]; y = w.ny ; yVar = a - w.c
    float py = 0.f, pv = 0.f;
    if (tid < KNN) {
        float w = A[tid][128] / A[tid][tid];
        py = w * nys[tid];
        pv = w * c0[tid];
    }
    #pragma unroll
    for (int o = 1; o < 64; o <<= 1) { py += __shfl_xor(py, o); pv += __shfl_xor(pv, o); }
    if ((tid & 63) == 0) { redf[tid >> 6] = py; redf[4 + (tid >> 6)] = pv; }
    __syncthreads();
    if (tid == 0) {
        float y = redf[0] + redf[1] + redf[2] + redf[3];
        float q = redf[4] + redf[5] + redf[6] + redf[7];
        out[row]         = y;
        out[BATCH + row] = aamp - q;
    }
}

extern "C" void kernel_launch(void* const* d_in, const int* in_sizes, int n_in,
                              void* d_out, int out_size, void* d_ws, size_t ws_size,
                              hipStream_t stream)
{
    const float* x  = (const float*)d_in[0];
    const float* tX = (const float*)d_in[1];
    const float* ty = (const float*)d_in[2];
    const float* pl = (const float*)d_in[3];
    const float* pa = (const float*)d_in[4];
    float* out = (float*)d_out;
    char* ws = (char*)d_ws;

    float*        thrv    = (float*)(ws + OFF_THR);
    unsigned int* gcnt    = (unsigned int*)(ws + OFF_CNT);
    int*          sel     = (int*)(ws + OFF_SEL);
    uint2*        cand    = (uint2*)(ws + OFF_CAND);
    float*        sampleV = (float*)(ws + OFF_CAND);  // aliased: consumed before cand is written

    hipMemsetAsync(gcnt, 0, BATCH * sizeof(unsigned int), stream);
    ksample<<<BATCH / BM, 256, 0, stream>>>(x, tX, sampleV);
    kthresh<<<BATCH, 256, 0, stream>>>(sampleV, thrv);
    kdist<<<(BATCH / BM) * NCHUNK, 256, 0, stream>>>(x, tX, thrv, gcnt, cand);
    kselect<<<BATCH, 256, 0, stream>>>(gcnt, cand, sel);
    ksolve<<<BATCH, 256, 0, stream>>>(x, tX, ty, sel, pl, pa, out);
}